// Round 8
// baseline (870.032 us; speedup 1.0000x reference)
//
#include <hip/hip_runtime.h>
#include <math.h>

#define H 60
#define EPSC 0.01f
#define ALPHAC 0.1f

typedef __attribute__((ext_vector_type(8)))  __bf16        bf16x8;
typedef __attribute__((ext_vector_type(4)))  float         f32x4;
typedef __attribute__((ext_vector_type(4)))  unsigned int  uint4v;

// ws layout (bytes):
//   [0, 24576)      A1 frags  ushort[12288]  (GEMM1 A: W2 rows,  m=j, k=i)
//   [24576, 49152)  A2 frags  ushort[12288]  (GEMM2 A: W2T rows, m=i, k=j)
//   [49152, 50176)  jconst    float4[64]     (b2, Wim2_0, Wim2_1, W3) zero-padded
//   [50176, 51200)  w1b1      float4[64]     (W1_0, W1_1, b1, 0) zero-padded
//   [51200, 51204)  h0        float
#define WS_A2_US   12288
#define WS_JC_B    49152
#define WS_WB_B    50176
#define WS_H0_B    51200

// ---------------------------------------------------------------------------
// Prep kernel (unchanged from R7 — verified correct): 3-level bf16 split of
// W2 in MFMA fragment order for both GEMMs + constant tables + h0.
// Fragment order (16x16x32 bf16): frag id f=(sig*4+tile)*2+kt; lane L owns
// element b at [m = 16*tile + (L&15)][k = 32*kt + 8*(L>>4) + b].
// ---------------------------------------------------------------------------
__global__ void dho_prep(const float* __restrict__ Xref, const float* __restrict__ W1,
                         const float* __restrict__ b1, const float* __restrict__ W2,
                         const float* __restrict__ b2, const float* __restrict__ W3,
                         const float* __restrict__ b3, const float* __restrict__ Wim2,
                         const float* __restrict__ Wim3, void* __restrict__ wsv)
{
    unsigned short* A1 = (unsigned short*)wsv;
    unsigned short* A2 = A1 + WS_A2_US;
    float4* jc  = (float4*)((char*)wsv + WS_JC_B);
    float4* wb  = (float4*)((char*)wsv + WS_WB_B);
    float*  h0o = (float*)((char*)wsv + WS_H0_B);
    const int t = threadIdx.x;

    for (int idx = t; idx < 24576; idx += 256) {
        int which = idx >= 12288;
        int rem   = which ? idx - 12288 : idx;
        int fid   = rem >> 9;
        int lane  = (rem >> 3) & 63;
        int b     = rem & 7;
        int sig   = fid >> 3;
        int tile  = (fid >> 1) & 3;
        int kt    = fid & 1;
        int m = 16 * tile + (lane & 15);
        int k = 32 * kt + 8 * (lane >> 4) + b;
        int j = which ? k : m;
        int i = which ? m : k;
        float w = (j < H && i < H) ? W2[j * H + i] : 0.0f;
        unsigned u0 = __float_as_uint(w) & 0xFFFF0000u;
        float r1 = w - __uint_as_float(u0);
        unsigned u1 = __float_as_uint(r1) & 0xFFFF0000u;
        float r2 = r1 - __uint_as_float(u1);
        unsigned u2 = __float_as_uint(r2) & 0xFFFF0000u;
        unsigned sel = (sig == 0) ? u0 : (sig == 1 ? u1 : u2);
        (which ? A2 : A1)[rem] = (unsigned short)(sel >> 16);
    }
    if (t < 64) {
        if (t < H) {
            jc[t] = make_float4(b2[t], Wim2[2 * t], Wim2[2 * t + 1], W3[t]);
            wb[t] = make_float4(W1[2 * t], W1[2 * t + 1], b1[t], 0.0f);
        } else {
            jc[t] = make_float4(0.f, 0.f, 0.f, 0.f);
            wb[t] = make_float4(0.f, 0.f, 0.f, 0.f);
        }
    }
    __shared__ float z1s[H], z2s[H];
    const float x0 = Xref[0], x1 = Xref[1];
    if (t < H) {
        float a = W1[2 * t] * x0 + W1[2 * t + 1] * x1 + b1[t];
        float e = expf(-fabsf(a));
        z1s[t] = logf(1.0f + e) + fmaxf(a, 0.0f);
    }
    __syncthreads();
    if (t < H) {
        float a = b2[t] + Wim2[2 * t] * x0 + Wim2[2 * t + 1] * x1;
        for (int i2 = 0; i2 < H; ++i2) a += W2[t * H + i2] * z1s[i2];
        float e = expf(-fabsf(a));
        z2s[t] = logf(1.0f + e) + fmaxf(a, 0.0f);
    }
    __syncthreads();
    if (t == 0) {
        float a = b3[0] + Wim3[0] * x0 + Wim3[1] * x1;
        for (int j2 = 0; j2 < H; ++j2) a += W3[j2] * z2s[j2];
        float e = expf(-fabsf(a));
        h0o[0] = logf(1.0f + e) + fmaxf(a, 0.0f);
    }
}

static __device__ __forceinline__ f32x4 mfma16(uint4v a, uint4v b, f32x4 c) {
    return __builtin_amdgcn_mfma_f32_16x16x32_bf16(
        __builtin_bit_cast(bf16x8, a), __builtin_bit_cast(bf16x8, b), c, 0, 0, 0);
}

// 3-level bf16 truncation split of 8 f32 -> three packed fragments
static __device__ __forceinline__ void split3(const float* v, uint4v& f0, uint4v& f1, uint4v& f2) {
    unsigned a[8], b[8], c[8];
#pragma unroll
    for (int e = 0; e < 8; ++e) {
        unsigned u0 = __float_as_uint(v[e]) & 0xFFFF0000u;
        float r1 = v[e] - __uint_as_float(u0);
        unsigned u1 = __float_as_uint(r1) & 0xFFFF0000u;
        float r2 = r1 - __uint_as_float(u1);
        unsigned u2 = __float_as_uint(r2) & 0xFFFF0000u;
        a[e] = u0; b[e] = u1; c[e] = u2;
    }
#pragma unroll
    for (int d = 0; d < 4; ++d) {
        f0[d] = (a[2 * d] >> 16) | (a[2 * d + 1] & 0xFFFF0000u);
        f1[d] = (b[2 * d] >> 16) | (b[2 * d + 1] & 0xFFFF0000u);
        f2[d] = (c[2 * d] >> 16) | (c[2 * d + 1] & 0xFFFF0000u);
    }
}

// sum across lanes {L, L^16, L^32, L^48} (same lane&15)
static __device__ __forceinline__ float redg(float v) {
    v += __shfl_xor(v, 16, 64);
    v += __shfl_xor(v, 32, 64);
    return v;
}

#define TSTR 68   // tbuf stride in floats: [16 samples][68] per wave

// ---------------------------------------------------------------------------
// Main kernel: 4 waves/block, 64 samples/wave as 4 sequential batches of 16.
// All W2 fragments live in LDS (staged once per block); per batch they are
// re-read with contiguous (conflict-free) ds_read_b128 -> per-thread live
// state stays ~80 VGPRs, under the compiler's 128 cap: no spills, no AGPR
// round-trips (R7's 139MB FETCH_SIZE scratch signature).
// t-transpose buffer is [sample][j] stride-68: b128 writes/reads, ~2-way max.
// ---------------------------------------------------------------------------
__global__ __launch_bounds__(256, 2) void dho_main(
    const float* __restrict__ X, const float* __restrict__ U,
    const void* __restrict__ wsv,
    const float* __restrict__ W_fnn, const float* __restrict__ W_gnn,
    const float* __restrict__ b_gnn, const float* __restrict__ b3,
    const float* __restrict__ Wim3, const float* __restrict__ Xref,
    float* __restrict__ out, int N)
{
    const float4* jcp = (const float4*)((const char*)wsv + WS_JC_B);
    const float4* wbp = (const float4*)((const char*)wsv + WS_WB_B);
    const float h0 = *(const float*)((const char*)wsv + WS_H0_B);

    __shared__ __align__(16) unsigned short sA[24576];  // A1 (12288) ++ A2 (12288)
    __shared__ __align__(16) float tbuf[4][16 * TSTR];  // per-wave t transpose

    const int tid = threadIdx.x;
    // stage fragments: 49152 B = 3072 x 16 B
    {
        const uint4v* src = (const uint4v*)wsv;
        uint4v* dst = (uint4v*)sA;
        for (int k = tid; k < 3072; k += 256) dst[k] = src[k];
    }
    __syncthreads();

    const uint4v* fA1 = (const uint4v*)sA;           // 1536 frags
    const uint4v* fA2 = ((const uint4v*)sA) + 1536;

    const int w  = tid >> 6;
    const int L  = tid & 63;
    const int g  = L >> 4;
    const int lm = L & 15;
    const int base = blockIdx.x * 256 + w * 64;
    float* tb = &tbuf[w][0];

    const float xr0 = Xref[0], xr1 = Xref[1];
    const float wim3_0 = Wim3[0], wim3_1 = Wim3[1];
    const float b3v = b3[0];
    const float fn0 = W_fnn[0], fn1 = W_fnn[1], fn2 = W_fnn[2], fn3 = W_fnn[3];
    const float gn0 = W_gnn[0], gn1 = W_gnn[1], gn2 = W_gnn[2], gn3 = W_gnn[3];
    const float bg0 = b_gnn[0], bg1 = b_gnn[1];

#pragma unroll 1
    for (int beta = 0; beta < 4; ++beta) {
        const int sid = base + 16 * beta + lm;
        const int sc  = sid < N ? sid : N - 1;
        const float2 x = ((const float2*)X)[sc];
        const float  u = U[sc];

        // ---- z1 fragments for this batch ----
        uint4v Zf[3][2];
#pragma unroll
        for (int kt = 0; kt < 2; ++kt) {
            float zv[8];
#pragma unroll
            for (int b = 0; b < 8; ++b) {
                int i = 32 * kt + 8 * g + b;
                float4 wv = wbp[i];
                float a1 = fmaf(wv.x, x.x, fmaf(wv.y, x.y, wv.z));
                float e1 = __expf(-fabsf(a1));
                float z = __logf(1.0f + e1) + fmaxf(a1, 0.0f);
                zv[b] = (i < H) ? z : 0.0f;
            }
            split3(zv, Zf[0][kt], Zf[1][kt], Zf[2][kt]);
        }

        // ---- GEMM1 + softplus block ----
        float a3p = 0.0f, q0p = 0.0f, q1p = 0.0f;
#pragma unroll
        for (int jt = 0; jt < 4; ++jt) {
            f32x4 acc = {0.0f, 0.0f, 0.0f, 0.0f};
#pragma unroll
            for (int kt = 0; kt < 2; ++kt) {
                uint4v A0 = fA1[((0 * 4 + jt) * 2 + kt) * 64 + L];
                uint4v A1v = fA1[((1 * 4 + jt) * 2 + kt) * 64 + L];
                uint4v A2v = fA1[((2 * 4 + jt) * 2 + kt) * 64 + L];
                acc = mfma16(A0,  Zf[0][kt], acc);
                acc = mfma16(A0,  Zf[1][kt], acc);
                acc = mfma16(A1v, Zf[0][kt], acc);
                acc = mfma16(A0,  Zf[2][kt], acc);
                acc = mfma16(A1v, Zf[1][kt], acc);
                acc = mfma16(A2v, Zf[0][kt], acc);
            }
            float4 tq;
#pragma unroll
            for (int r = 0; r < 4; ++r) {
                int j = 16 * jt + 4 * g + r;
                float4 jc = jcp[j];
                float a2 = acc[r] + jc.x + jc.y * x.x + jc.z * x.y;
                float e = __expf(-fabsf(a2));
                float inv = __builtin_amdgcn_rcpf(1.0f + e);
                float z2 = __logf(1.0f + e) + fmaxf(a2, 0.0f);
                float s2 = (a2 >= 0.0f ? 1.0f : e) * inv;
                a3p = fmaf(jc.w, z2, a3p);
                float tv = jc.w * s2;
                q0p = fmaf(tv, jc.y, q0p);
                q1p = fmaf(tv, jc.z, q1p);
                ((float*)&tq)[r] = tv;
            }
            *(float4*)&tb[lm * TSTR + 16 * jt + 4 * g] = tq;
        }
        float a3 = redg(a3p) + b3v + wim3_0 * x.x + wim3_1 * x.y;
        float qa = wim3_0 + redg(q0p);
        float qb = wim3_1 + redg(q1p);
        float e3 = __expf(-fabsf(a3));
        float inv3 = __builtin_amdgcn_rcpf(1.0f + e3);
        float hX = __logf(1.0f + e3) + fmaxf(a3, 0.0f);
        float s3 = (a3 >= 0.0f ? 1.0f : e3) * inv3;
        float h = hX - h0;
        float sigma, sigp;
        if (h >= 1.0f)      { sigma = h - 0.5f;      sigp = 1.0f; }
        else if (h > 0.0f)  { sigma = 0.5f * h * h;  sigp = h; }
        else                { sigma = 0.0f;          sigp = 0.0f; }
        float dx0 = x.x - xr0, dx1 = x.y - xr1;
        float V = sigma + EPSC * (dx0 * dx0 + dx1 * dx1);

        // ---- t fragments (transpose via per-wave LDS) ----
        uint4v Tf[3][2];
#pragma unroll
        for (int kt = 0; kt < 2; ++kt) {
            float tv[8];
            *(float4*)&tv[0] = *(const float4*)&tb[lm * TSTR + 32 * kt + 8 * g];
            *(float4*)&tv[4] = *(const float4*)&tb[lm * TSTR + 32 * kt + 8 * g + 4];
            split3(tv, Tf[0][kt], Tf[1][kt], Tf[2][kt]);
        }

        // ---- GEMM2 + layer-1 backprop fold ----
        float p0 = 0.0f, p1 = 0.0f;
#pragma unroll
        for (int it = 0; it < 4; ++it) {
            f32x4 acc = {0.0f, 0.0f, 0.0f, 0.0f};
#pragma unroll
            for (int kt = 0; kt < 2; ++kt) {
                uint4v A0 = fA2[((0 * 4 + it) * 2 + kt) * 64 + L];
                uint4v A1v = fA2[((1 * 4 + it) * 2 + kt) * 64 + L];
                uint4v A2v = fA2[((2 * 4 + it) * 2 + kt) * 64 + L];
                acc = mfma16(A0,  Tf[0][kt], acc);
                acc = mfma16(A0,  Tf[1][kt], acc);
                acc = mfma16(A1v, Tf[0][kt], acc);
                acc = mfma16(A0,  Tf[2][kt], acc);
                acc = mfma16(A1v, Tf[1][kt], acc);
                acc = mfma16(A2v, Tf[0][kt], acc);
            }
#pragma unroll
            for (int r = 0; r < 4; ++r) {
                int i = 16 * it + 4 * g + r;
                float4 wv = wbp[i];
                float a1 = fmaf(wv.x, x.x, fmaf(wv.y, x.y, wv.z));
                float e1 = __expf(-fabsf(a1));
                float s1 = (a1 >= 0.0f ? 1.0f : e1) * __builtin_amdgcn_rcpf(1.0f + e1);
                float c = acc[r] * s1;       // pads: acc=0 -> c=0
                p0 = fmaf(c, wv.x, p0);
                p1 = fmaf(c, wv.y, p1);
            }
        }
        float sum0 = redg(p0), sum1 = redg(p1);

        // ---- epilogue ----
        float dh0 = s3 * (qa + sum0);
        float dh1 = s3 * (qb + sum1);
        float dV0 = sigp * dh0 + 2.0f * EPSC * dx0;
        float dV1 = sigp * dh1 + 2.0f * EPSC * dx1;
        float f0 = fn0 * x.x + fn1 * x.y;
        float f1 = fn2 * x.x + fn3 * x.y;
        float gg0 = gn0 * x.x + gn1 * x.y + bg0;
        float gg1 = gn2 * x.x + gn3 * x.y + bg1;
        float scv = dV0 * f0 + dV1 * f1 + ALPHAC * V - fabsf(dV0 * gg0 + dV1 * gg1);
        float nrm = dV0 * dV0 + dV1 * dV1;
        float rr = fmaxf(scv, 0.0f) * __builtin_amdgcn_rcpf(nrm);
        float o0 = f0 - dV0 * rr + gg0 * u;
        float o1 = f1 - dV1 * rr + gg1 * u;
        if (g == 0 && sid < N) ((float2*)out)[sid] = make_float2(o0, o1);
    }
}

extern "C" void kernel_launch(void* const* d_in, const int* in_sizes, int n_in,
                              void* d_out, int out_size, void* d_ws, size_t ws_size,
                              hipStream_t stream) {
    // 0:X 1:U 2:Xref 3:W_fnn 4:W_gnn 5:b_gnn 6:W1 7:b1 8:W2 9:b2 10:W3 11:b3 12:Wim2 13:Wim3
    const float* X     = (const float*)d_in[0];
    const float* U     = (const float*)d_in[1];
    const float* Xref  = (const float*)d_in[2];
    const float* W_fnn = (const float*)d_in[3];
    const float* W_gnn = (const float*)d_in[4];
    const float* b_gnn = (const float*)d_in[5];
    const float* W1    = (const float*)d_in[6];
    const float* b1    = (const float*)d_in[7];
    const float* W2    = (const float*)d_in[8];
    const float* b2    = (const float*)d_in[9];
    const float* W3    = (const float*)d_in[10];
    const float* b3    = (const float*)d_in[11];
    const float* Wim2  = (const float*)d_in[12];
    const float* Wim3  = (const float*)d_in[13];

    const int N = in_sizes[0] / 2;
    float* outp = (float*)d_out;

    dho_prep<<<1, 256, 0, stream>>>(Xref, W1, b1, W2, b2, W3, b3, Wim2, Wim3, d_ws);

    const int blocks = (N + 255) / 256;
    dho_main<<<blocks, 256, 0, stream>>>(
        X, U, d_ws, W_fnn, W_gnn, b_gnn, b3, Wim3, Xref, outp, N);
}

// Round 9
// 439.408 us; speedup vs baseline: 1.9800x; 1.9800x over previous
//
#include <hip/hip_runtime.h>
#include <math.h>

#define H 60
#define EPSC 0.01f
#define ALPHAC 0.1f

typedef __attribute__((ext_vector_type(8)))  __bf16        bf16x8;
typedef __attribute__((ext_vector_type(4)))  float         f32x4;
typedef __attribute__((ext_vector_type(4)))  unsigned int  uint4v;

// ws layout (bytes):
//   [0, 24576)      A1 frags  ushort[12288]  (GEMM1 A: W2 rows,  m=j, k=i)
//   [24576, 49152)  A2 frags  ushort[12288]  (GEMM2 A: W2T rows, m=i, k=j)
//   [49152, 50176)  jconst    float4[64]     (b2, Wim2_0, Wim2_1, W3) zero-padded
//   [50176, 51200)  w1b1      float4[64]     (W1_0, W1_1, b1, 0) zero-padded
//   [51200, 51204)  h0        float
#define WS_A2_US   12288
#define WS_JC_B    49152
#define WS_WB_B    50176
#define WS_H0_B    51200

// ---------------------------------------------------------------------------
// Prep kernel (unchanged — verified across R7/R8): 3-level bf16 split of W2
// in MFMA fragment order for both GEMMs + constant tables + h0.
// Fragment order (16x16x32 bf16): frag id f=(sig*4+tile)*2+kt; lane L owns
// element b at [m = 16*tile + (L&15)][k = 32*kt + 8*(L>>4) + b].
// ---------------------------------------------------------------------------
__global__ void dho_prep(const float* __restrict__ Xref, const float* __restrict__ W1,
                         const float* __restrict__ b1, const float* __restrict__ W2,
                         const float* __restrict__ b2, const float* __restrict__ W3,
                         const float* __restrict__ b3, const float* __restrict__ Wim2,
                         const float* __restrict__ Wim3, void* __restrict__ wsv)
{
    unsigned short* A1 = (unsigned short*)wsv;
    unsigned short* A2 = A1 + WS_A2_US;
    float4* jc  = (float4*)((char*)wsv + WS_JC_B);
    float4* wb  = (float4*)((char*)wsv + WS_WB_B);
    float*  h0o = (float*)((char*)wsv + WS_H0_B);
    const int t = threadIdx.x;

    for (int idx = t; idx < 24576; idx += 256) {
        int which = idx >= 12288;
        int rem   = which ? idx - 12288 : idx;
        int fid   = rem >> 9;
        int lane  = (rem >> 3) & 63;
        int b     = rem & 7;
        int sig   = fid >> 3;
        int tile  = (fid >> 1) & 3;
        int kt    = fid & 1;
        int m = 16 * tile + (lane & 15);
        int k = 32 * kt + 8 * (lane >> 4) + b;
        int j = which ? k : m;
        int i = which ? m : k;
        float w = (j < H && i < H) ? W2[j * H + i] : 0.0f;
        unsigned u0 = __float_as_uint(w) & 0xFFFF0000u;
        float r1 = w - __uint_as_float(u0);
        unsigned u1 = __float_as_uint(r1) & 0xFFFF0000u;
        float r2 = r1 - __uint_as_float(u1);
        unsigned u2 = __float_as_uint(r2) & 0xFFFF0000u;
        unsigned sel = (sig == 0) ? u0 : (sig == 1 ? u1 : u2);
        (which ? A2 : A1)[rem] = (unsigned short)(sel >> 16);
    }
    if (t < 64) {
        if (t < H) {
            jc[t] = make_float4(b2[t], Wim2[2 * t], Wim2[2 * t + 1], W3[t]);
            wb[t] = make_float4(W1[2 * t], W1[2 * t + 1], b1[t], 0.0f);
        } else {
            jc[t] = make_float4(0.f, 0.f, 0.f, 0.f);
            wb[t] = make_float4(0.f, 0.f, 0.f, 0.f);
        }
    }
    __shared__ float z1s[H], z2s[H];
    const float x0 = Xref[0], x1 = Xref[1];
    if (t < H) {
        float a = W1[2 * t] * x0 + W1[2 * t + 1] * x1 + b1[t];
        float e = expf(-fabsf(a));
        z1s[t] = logf(1.0f + e) + fmaxf(a, 0.0f);
    }
    __syncthreads();
    if (t < H) {
        float a = b2[t] + Wim2[2 * t] * x0 + Wim2[2 * t + 1] * x1;
        for (int i2 = 0; i2 < H; ++i2) a += W2[t * H + i2] * z1s[i2];
        float e = expf(-fabsf(a));
        z2s[t] = logf(1.0f + e) + fmaxf(a, 0.0f);
    }
    __syncthreads();
    if (t == 0) {
        float a = b3[0] + Wim3[0] * x0 + Wim3[1] * x1;
        for (int j2 = 0; j2 < H; ++j2) a += W3[j2] * z2s[j2];
        float e = expf(-fabsf(a));
        h0o[0] = logf(1.0f + e) + fmaxf(a, 0.0f);
    }
}

static __device__ __forceinline__ f32x4 mfma16(uint4v a, uint4v b, f32x4 c) {
    return __builtin_amdgcn_mfma_f32_16x16x32_bf16(
        __builtin_bit_cast(bf16x8, a), __builtin_bit_cast(bf16x8, b), c, 0, 0, 0);
}

// 3-level bf16 truncation split of 8 f32 -> three packed fragments
static __device__ __forceinline__ void split3(const float* v, uint4v& f0, uint4v& f1, uint4v& f2) {
    unsigned a[8], b[8], c[8];
#pragma unroll
    for (int e = 0; e < 8; ++e) {
        unsigned u0 = __float_as_uint(v[e]) & 0xFFFF0000u;
        float r1 = v[e] - __uint_as_float(u0);
        unsigned u1 = __float_as_uint(r1) & 0xFFFF0000u;
        float r2 = r1 - __uint_as_float(u1);
        unsigned u2 = __float_as_uint(r2) & 0xFFFF0000u;
        a[e] = u0; b[e] = u1; c[e] = u2;
    }
#pragma unroll
    for (int d = 0; d < 4; ++d) {
        f0[d] = (a[2 * d] >> 16) | (a[2 * d + 1] & 0xFFFF0000u);
        f1[d] = (b[2 * d] >> 16) | (b[2 * d + 1] & 0xFFFF0000u);
        f2[d] = (c[2 * d] >> 16) | (c[2 * d + 1] & 0xFFFF0000u);
    }
}

// sum across lanes {L, L^16, L^32, L^48} (same lane&15)
static __device__ __forceinline__ float redg(float v) {
    v += __shfl_xor(v, 16, 64);
    v += __shfl_xor(v, 32, 64);
    return v;
}

#define TSTR 68   // tbuf per-sample stride in floats

// ---------------------------------------------------------------------------
// Main kernel: R7's two-phase fragment-pinned structure (A-fragments pinned
// in registers -> AGPRs; MFMA reads A/B from AGPR natively so that's free),
// with R7's one observed spill source (8x[4] per-beta register state arrays,
// 32 floats/thread == the 139MB FETCH signature) moved to an 8KB LDS table.
// tbuf is [sample][68] (R8 layout, conflicts 4M->1M). sched_barrier(0) after
// each beta iteration forbids the cross-iteration load hoisting that caused
// R8's 2.8GB scratch catastrophe.
// ---------------------------------------------------------------------------
__global__ __launch_bounds__(256, 2) void dho_main(
    const float* __restrict__ X, const float* __restrict__ U,
    const void* __restrict__ wsv,
    const float* __restrict__ W_fnn, const float* __restrict__ W_gnn,
    const float* __restrict__ b_gnn, const float* __restrict__ b3,
    const float* __restrict__ Wim3, const float* __restrict__ Xref,
    float* __restrict__ out, int N)
{
    const uint4v* fA1 = (const uint4v*)wsv;            // 1536 frags
    const uint4v* fA2 = ((const uint4v*)wsv) + 1536;
    const float4* jcp = (const float4*)((const char*)wsv + WS_JC_B);
    const float4* wbp = (const float4*)((const char*)wsv + WS_WB_B);
    const float h0 = *(const float*)((const char*)wsv + WS_H0_B);

    __shared__ __align__(16) float tbuf[16 * (16 * TSTR)];  // [w*4+beta][16][68]
    __shared__ __align__(16) float sSt[256 * 8];            // [sample-in-block][8]

    const int tid = threadIdx.x;
    const int w  = tid >> 6;
    const int L  = tid & 63;
    const int g  = L >> 4;
    const int lm = L & 15;
    const int base = blockIdx.x * 256 + w * 64;

    const float xr0 = Xref[0], xr1 = Xref[1];
    const float wim3_0 = Wim3[0], wim3_1 = Wim3[1];
    const float b3v = b3[0];
    const float fn0 = W_fnn[0], fn1 = W_fnn[1], fn2 = W_fnn[2], fn3 = W_fnn[3];
    const float gn0 = W_gnn[0], gn1 = W_gnn[1], gn2 = W_gnn[2], gn3 = W_gnn[3];
    const float bg0 = b_gnn[0], bg1 = b_gnn[1];

    // ---- pin GEMM1 A-fragments (96 regs -> AGPR-class; free for MFMA) ----
    uint4v Af[3][4][2];
#pragma unroll
    for (int s = 0; s < 3; ++s)
#pragma unroll
        for (int tl = 0; tl < 4; ++tl)
#pragma unroll
            for (int kt = 0; kt < 2; ++kt)
                Af[s][tl][kt] = fA1[((s * 4 + tl) * 2 + kt) * 64 + L];

    // ================= phase 1: forward =================
#pragma unroll 1
    for (int beta = 0; beta < 4; ++beta) {
        const int sid = base + 16 * beta + lm;
        const int sc  = sid < N ? sid : N - 1;
        const float2 x = ((const float2*)X)[sc];
        const float  u = U[sc];
        float* tb = &tbuf[(w * 4 + beta) * (16 * TSTR)];

        // z1 fragments
        uint4v Zf[3][2];
#pragma unroll
        for (int kt = 0; kt < 2; ++kt) {
            float zv[8];
#pragma unroll
            for (int b = 0; b < 8; ++b) {
                int i = 32 * kt + 8 * g + b;
                float4 wv = wbp[i];
                float a1 = fmaf(wv.x, x.x, fmaf(wv.y, x.y, wv.z));
                float e1 = __expf(-fabsf(a1));
                float z = __logf(1.0f + e1) + fmaxf(a1, 0.0f);
                zv[b] = (i < H) ? z : 0.0f;
            }
            split3(zv, Zf[0][kt], Zf[1][kt], Zf[2][kt]);
        }

        // GEMM1 + softplus block
        float a3p = 0.0f, q0p = 0.0f, q1p = 0.0f;
#pragma unroll
        for (int jt = 0; jt < 4; ++jt) {
            f32x4 acc = {0.0f, 0.0f, 0.0f, 0.0f};
#pragma unroll
            for (int kt = 0; kt < 2; ++kt) {
                acc = mfma16(Af[0][jt][kt], Zf[0][kt], acc);
                acc = mfma16(Af[0][jt][kt], Zf[1][kt], acc);
                acc = mfma16(Af[1][jt][kt], Zf[0][kt], acc);
                acc = mfma16(Af[0][jt][kt], Zf[2][kt], acc);
                acc = mfma16(Af[1][jt][kt], Zf[1][kt], acc);
                acc = mfma16(Af[2][jt][kt], Zf[0][kt], acc);
            }
            float4 tq;
#pragma unroll
            for (int r = 0; r < 4; ++r) {
                int j = 16 * jt + 4 * g + r;
                float4 jc = jcp[j];
                float a2 = acc[r] + jc.x + jc.y * x.x + jc.z * x.y;
                float e = __expf(-fabsf(a2));
                float inv = __builtin_amdgcn_rcpf(1.0f + e);
                float z2 = __logf(1.0f + e) + fmaxf(a2, 0.0f);
                float s2 = (a2 >= 0.0f ? 1.0f : e) * inv;
                a3p = fmaf(jc.w, z2, a3p);
                float tv = jc.w * s2;
                q0p = fmaf(tv, jc.y, q0p);
                q1p = fmaf(tv, jc.z, q1p);
                ((float*)&tq)[r] = tv;
            }
            *(float4*)&tb[lm * TSTR + 16 * jt + 4 * g] = tq;
        }

        float a3 = redg(a3p) + b3v + wim3_0 * x.x + wim3_1 * x.y;
        float qa = wim3_0 + redg(q0p);
        float qb = wim3_1 + redg(q1p);
        float e3 = __expf(-fabsf(a3));
        float inv3 = __builtin_amdgcn_rcpf(1.0f + e3);
        float hX = __logf(1.0f + e3) + fmaxf(a3, 0.0f);
        float s3 = (a3 >= 0.0f ? 1.0f : e3) * inv3;
        float h = hX - h0;
        float sigma, sigp;
        if (h >= 1.0f)      { sigma = h - 0.5f;      sigp = 1.0f; }
        else if (h > 0.0f)  { sigma = 0.5f * h * h;  sigp = h; }
        else                { sigma = 0.0f;          sigp = 0.0f; }
        float dx0 = x.x - xr0, dx1 = x.y - xr1;
        float V = sigma + EPSC * (dx0 * dx0 + dx1 * dx1);

        // per-sample state -> LDS (g==0 lanes own the write)
        if (g == 0) {
            float* st = &sSt[(w * 64 + beta * 16 + lm) * 8];
            *(float4*)&st[0] = make_float4(x.x, x.y, u, s3);
            *(float4*)&st[4] = make_float4(sigp, V, qa, qb);
        }
        __builtin_amdgcn_sched_barrier(0);
    }

    __syncthreads();   // tbuf + sSt fully written

    // ---- pin GEMM2 A-fragments (reuse Af) ----
#pragma unroll
    for (int s = 0; s < 3; ++s)
#pragma unroll
        for (int tl = 0; tl < 4; ++tl)
#pragma unroll
            for (int kt = 0; kt < 2; ++kt)
                Af[s][tl][kt] = fA2[((s * 4 + tl) * 2 + kt) * 64 + L];

    // ================= phase 2: backward + epilogue =================
#pragma unroll 1
    for (int beta = 0; beta < 4; ++beta) {
        const int sid = base + 16 * beta + lm;
        const float* st = &sSt[(w * 64 + beta * 16 + lm) * 8];
        const float4 st0 = *(const float4*)&st[0];   // x0, x1, u, s3
        const float4 st1 = *(const float4*)&st[4];   // sigp, V, qa, qb
        const float x0v = st0.x, x1v = st0.y;
        float* tb = &tbuf[(w * 4 + beta) * (16 * TSTR)];

        // t fragments from LDS transpose buffer
        uint4v Tf[3][2];
#pragma unroll
        for (int kt = 0; kt < 2; ++kt) {
            float tv[8];
            *(float4*)&tv[0] = *(const float4*)&tb[lm * TSTR + 32 * kt + 8 * g];
            *(float4*)&tv[4] = *(const float4*)&tb[lm * TSTR + 32 * kt + 8 * g + 4];
            split3(tv, Tf[0][kt], Tf[1][kt], Tf[2][kt]);
        }

        // GEMM2 + layer-1 backprop fold
        float p0 = 0.0f, p1 = 0.0f;
#pragma unroll
        for (int it = 0; it < 4; ++it) {
            f32x4 acc = {0.0f, 0.0f, 0.0f, 0.0f};
#pragma unroll
            for (int kt = 0; kt < 2; ++kt) {
                acc = mfma16(Af[0][it][kt], Tf[0][kt], acc);
                acc = mfma16(Af[0][it][kt], Tf[1][kt], acc);
                acc = mfma16(Af[1][it][kt], Tf[0][kt], acc);
                acc = mfma16(Af[0][it][kt], Tf[2][kt], acc);
                acc = mfma16(Af[1][it][kt], Tf[1][kt], acc);
                acc = mfma16(Af[2][it][kt], Tf[0][kt], acc);
            }
#pragma unroll
            for (int r = 0; r < 4; ++r) {
                int i = 16 * it + 4 * g + r;
                float4 wv = wbp[i];
                float a1 = fmaf(wv.x, x0v, fmaf(wv.y, x1v, wv.z));
                float e1 = __expf(-fabsf(a1));
                float s1 = (a1 >= 0.0f ? 1.0f : e1) * __builtin_amdgcn_rcpf(1.0f + e1);
                float c = acc[r] * s1;       // pads: acc=0 -> c=0
                p0 = fmaf(c, wv.x, p0);
                p1 = fmaf(c, wv.y, p1);
            }
        }
        float sum0 = redg(p0), sum1 = redg(p1);

        // epilogue
        float s3 = st0.w, sigp = st1.x, V = st1.y;
        float dh0 = s3 * (st1.z + sum0);
        float dh1 = s3 * (st1.w + sum1);
        float dx0 = x0v - xr0, dx1 = x1v - xr1;
        float dV0 = sigp * dh0 + 2.0f * EPSC * dx0;
        float dV1 = sigp * dh1 + 2.0f * EPSC * dx1;
        float f0 = fn0 * x0v + fn1 * x1v;
        float f1 = fn2 * x0v + fn3 * x1v;
        float gg0 = gn0 * x0v + gn1 * x1v + bg0;
        float gg1 = gn2 * x0v + gn3 * x1v + bg1;
        float scv = dV0 * f0 + dV1 * f1 + ALPHAC * V - fabsf(dV0 * gg0 + dV1 * gg1);
        float nrm = dV0 * dV0 + dV1 * dV1;
        float rr = fmaxf(scv, 0.0f) * __builtin_amdgcn_rcpf(nrm);
        float o0 = f0 - dV0 * rr + gg0 * st0.z;
        float o1 = f1 - dV1 * rr + gg1 * st0.z;
        if (g == 0 && sid < N) ((float2*)out)[sid] = make_float2(o0, o1);
        __builtin_amdgcn_sched_barrier(0);
    }
}

extern "C" void kernel_launch(void* const* d_in, const int* in_sizes, int n_in,
                              void* d_out, int out_size, void* d_ws, size_t ws_size,
                              hipStream_t stream) {
    // 0:X 1:U 2:Xref 3:W_fnn 4:W_gnn 5:b_gnn 6:W1 7:b1 8:W2 9:b2 10:W3 11:b3 12:Wim2 13:Wim3
    const float* X     = (const float*)d_in[0];
    const float* U     = (const float*)d_in[1];
    const float* Xref  = (const float*)d_in[2];
    const float* W_fnn = (const float*)d_in[3];
    const float* W_gnn = (const float*)d_in[4];
    const float* b_gnn = (const float*)d_in[5];
    const float* W1    = (const float*)d_in[6];
    const float* b1    = (const float*)d_in[7];
    const float* W2    = (const float*)d_in[8];
    const float* b2    = (const float*)d_in[9];
    const float* W3    = (const float*)d_in[10];
    const float* b3    = (const float*)d_in[11];
    const float* Wim2  = (const float*)d_in[12];
    const float* Wim3  = (const float*)d_in[13];

    const int N = in_sizes[0] / 2;
    float* outp = (float*)d_out;

    dho_prep<<<1, 256, 0, stream>>>(Xref, W1, b1, W2, b2, W3, b3, Wim2, Wim3, d_ws);

    const int blocks = (N + 255) / 256;
    dho_main<<<blocks, 256, 0, stream>>>(
        X, U, d_ws, W_fnn, W_gnn, b_gnn, b3, Wim3, Xref, outp, N);
}

// Round 10
// 237.465 us; speedup vs baseline: 3.6638x; 1.8504x over previous
//
#include <hip/hip_runtime.h>
#include <math.h>

#define H 60
#define EPSC 0.01f
#define ALPHAC 0.1f

typedef __attribute__((ext_vector_type(8)))  __bf16        bf16x8;
typedef __attribute__((ext_vector_type(4)))  float         f32x4;
typedef __attribute__((ext_vector_type(4)))  unsigned int  uint4v;

// ws layout (bytes):
//   [0, 24576)      A1 frags  ushort[12288]  (GEMM1 A: W2 rows,  m=j, k=i)
//   [24576, 49152)  A2 frags  ushort[12288]  (GEMM2 A: W2T rows, m=i, k=j)
//   [49152, 50176)  jconst    float4[64]     (b2, Wim2_0, Wim2_1, W3) zero-padded
//   [50176, 51200)  w1b1      float4[64]     (W1_0, W1_1, b1, 0) zero-padded
//   [51200, 51204)  h0        float
#define WS_A2_US   12288
#define WS_JC_B    49152
#define WS_WB_B    50176
#define WS_H0_B    51200

// ---------------------------------------------------------------------------
// Prep kernel (unchanged — verified across R7/R8/R9): 3-level bf16 split of
// W2 in MFMA fragment order for both GEMMs + constant tables + h0.
// Fragment order (16x16x32 bf16): frag id f=(sig*4+tile)*2+kt; lane L owns
// element b at [m = 16*tile + (L&15)][k = 32*kt + 8*(L>>4) + b].
// ---------------------------------------------------------------------------
__global__ void dho_prep(const float* __restrict__ Xref, const float* __restrict__ W1,
                         const float* __restrict__ b1, const float* __restrict__ W2,
                         const float* __restrict__ b2, const float* __restrict__ W3,
                         const float* __restrict__ b3, const float* __restrict__ Wim2,
                         const float* __restrict__ Wim3, void* __restrict__ wsv)
{
    unsigned short* A1 = (unsigned short*)wsv;
    unsigned short* A2 = A1 + WS_A2_US;
    float4* jc  = (float4*)((char*)wsv + WS_JC_B);
    float4* wb  = (float4*)((char*)wsv + WS_WB_B);
    float*  h0o = (float*)((char*)wsv + WS_H0_B);
    const int t = threadIdx.x;

    for (int idx = t; idx < 24576; idx += 256) {
        int which = idx >= 12288;
        int rem   = which ? idx - 12288 : idx;
        int fid   = rem >> 9;
        int lane  = (rem >> 3) & 63;
        int b     = rem & 7;
        int sig   = fid >> 3;
        int tile  = (fid >> 1) & 3;
        int kt    = fid & 1;
        int m = 16 * tile + (lane & 15);
        int k = 32 * kt + 8 * (lane >> 4) + b;
        int j = which ? k : m;
        int i = which ? m : k;
        float w = (j < H && i < H) ? W2[j * H + i] : 0.0f;
        unsigned u0 = __float_as_uint(w) & 0xFFFF0000u;
        float r1 = w - __uint_as_float(u0);
        unsigned u1 = __float_as_uint(r1) & 0xFFFF0000u;
        float r2 = r1 - __uint_as_float(u1);
        unsigned u2 = __float_as_uint(r2) & 0xFFFF0000u;
        unsigned sel = (sig == 0) ? u0 : (sig == 1 ? u1 : u2);
        (which ? A2 : A1)[rem] = (unsigned short)(sel >> 16);
    }
    if (t < 64) {
        if (t < H) {
            jc[t] = make_float4(b2[t], Wim2[2 * t], Wim2[2 * t + 1], W3[t]);
            wb[t] = make_float4(W1[2 * t], W1[2 * t + 1], b1[t], 0.0f);
        } else {
            jc[t] = make_float4(0.f, 0.f, 0.f, 0.f);
            wb[t] = make_float4(0.f, 0.f, 0.f, 0.f);
        }
    }
    __shared__ float z1s[H], z2s[H];
    const float x0 = Xref[0], x1 = Xref[1];
    if (t < H) {
        float a = W1[2 * t] * x0 + W1[2 * t + 1] * x1 + b1[t];
        float e = expf(-fabsf(a));
        z1s[t] = logf(1.0f + e) + fmaxf(a, 0.0f);
    }
    __syncthreads();
    if (t < H) {
        float a = b2[t] + Wim2[2 * t] * x0 + Wim2[2 * t + 1] * x1;
        for (int i2 = 0; i2 < H; ++i2) a += W2[t * H + i2] * z1s[i2];
        float e = expf(-fabsf(a));
        z2s[t] = logf(1.0f + e) + fmaxf(a, 0.0f);
    }
    __syncthreads();
    if (t == 0) {
        float a = b3[0] + Wim3[0] * x0 + Wim3[1] * x1;
        for (int j2 = 0; j2 < H; ++j2) a += W3[j2] * z2s[j2];
        float e = expf(-fabsf(a));
        h0o[0] = logf(1.0f + e) + fmaxf(a, 0.0f);
    }
}

static __device__ __forceinline__ f32x4 mfma16(uint4v a, uint4v b, f32x4 c) {
    return __builtin_amdgcn_mfma_f32_16x16x32_bf16(
        __builtin_bit_cast(bf16x8, a), __builtin_bit_cast(bf16x8, b), c, 0, 0, 0);
}

// 3-level bf16 truncation split of 8 f32 -> three packed fragments
static __device__ __forceinline__ void split3(const float* v, uint4v& f0, uint4v& f1, uint4v& f2) {
    unsigned a[8], b[8], c[8];
#pragma unroll
    for (int e = 0; e < 8; ++e) {
        unsigned u0 = __float_as_uint(v[e]) & 0xFFFF0000u;
        float r1 = v[e] - __uint_as_float(u0);
        unsigned u1 = __float_as_uint(r1) & 0xFFFF0000u;
        float r2 = r1 - __uint_as_float(u1);
        unsigned u2 = __float_as_uint(r2) & 0xFFFF0000u;
        a[e] = u0; b[e] = u1; c[e] = u2;
    }
#pragma unroll
    for (int d = 0; d < 4; ++d) {
        f0[d] = (a[2 * d] >> 16) | (a[2 * d + 1] & 0xFFFF0000u);
        f1[d] = (b[2 * d] >> 16) | (b[2 * d + 1] & 0xFFFF0000u);
        f2[d] = (c[2 * d] >> 16) | (c[2 * d + 1] & 0xFFFF0000u);
    }
}

// sum across lanes {L, L^16, L^32, L^48} (same lane&15)
static __device__ __forceinline__ float redg(float v) {
    v += __shfl_xor(v, 16, 64);
    v += __shfl_xor(v, 32, 64);
    return v;
}

#define TSTR 68   // tbuf per-sample stride in floats (2-way bank alias max)

// ---------------------------------------------------------------------------
// Main kernel, R10: single-phase per-beta pipeline (R8 dataflow) with LDS-
// streamed fragments under `#pragma unroll 1` jt/it loops.
// Why: R7/R9 proved MFMA A/B operands are VGPR-class only (pinned fragments
// spill to scratch past the hard 128-VGPR cap: 139MB/310MB FETCH signatures);
// R8 proved LDS streaming works but full jt-unroll let the scheduler hoist
// all 48 ds_reads (2.8GB scratch). unroll-1 keeps exactly one iteration's 6
// fragment loads (24 regs) live -> peak ~85 VGPRs, nothing to spill.
// Two acc chains (kt0/kt1) halve the MFMA dependency chain.
// ---------------------------------------------------------------------------
__global__ __launch_bounds__(256, 2) void dho_main(
    const float* __restrict__ X, const float* __restrict__ U,
    const void* __restrict__ wsv,
    const float* __restrict__ W_fnn, const float* __restrict__ W_gnn,
    const float* __restrict__ b_gnn, const float* __restrict__ b3,
    const float* __restrict__ Wim3, const float* __restrict__ Xref,
    float* __restrict__ out, int N)
{
    const float4* jcp = (const float4*)((const char*)wsv + WS_JC_B);
    const float4* wbp = (const float4*)((const char*)wsv + WS_WB_B);
    const float h0 = *(const float*)((const char*)wsv + WS_H0_B);

    __shared__ __align__(16) unsigned short sA[24576];   // A1 ++ A2 = 48 KB
    __shared__ __align__(16) float tbuf[4][16 * TSTR];   // per-wave t transpose

    const int tid = threadIdx.x;
    {
        const uint4v* src = (const uint4v*)wsv;
        uint4v* dst = (uint4v*)sA;
#pragma unroll 1
        for (int k = tid; k < 3072; k += 256) dst[k] = src[k];
    }
    __syncthreads();

    const uint4v* fA1 = (const uint4v*)sA;           // 1536 frags
    const uint4v* fA2 = ((const uint4v*)sA) + 1536;

    const int w  = tid >> 6;
    const int L  = tid & 63;
    const int g  = L >> 4;
    const int lm = L & 15;
    const int base = blockIdx.x * 256 + w * 64;
    float* tb = &tbuf[w][0];

    const float xr0 = Xref[0], xr1 = Xref[1];
    const float wim3_0 = Wim3[0], wim3_1 = Wim3[1];
    const float b3v = b3[0];
    const float fn0 = W_fnn[0], fn1 = W_fnn[1], fn2 = W_fnn[2], fn3 = W_fnn[3];
    const float gn0 = W_gnn[0], gn1 = W_gnn[1], gn2 = W_gnn[2], gn3 = W_gnn[3];
    const float bg0 = b_gnn[0], bg1 = b_gnn[1];

#pragma unroll 1
    for (int beta = 0; beta < 4; ++beta) {
        const int sid = base + 16 * beta + lm;
        const int sc  = sid < N ? sid : N - 1;
        const float2 x = ((const float2*)X)[sc];
        const float  u = U[sc];

        // ---- z1 fragments for this batch ----
        uint4v Zf[3][2];
#pragma unroll
        for (int kt = 0; kt < 2; ++kt) {
            float zv[8];
#pragma unroll
            for (int b = 0; b < 8; ++b) {
                int i = 32 * kt + 8 * g + b;
                float4 wv = wbp[i];
                float a1 = fmaf(wv.x, x.x, fmaf(wv.y, x.y, wv.z));
                float e1 = __expf(-fabsf(a1));
                float z = __logf(1.0f + e1) + fmaxf(a1, 0.0f);
                zv[b] = (i < H) ? z : 0.0f;
            }
            split3(zv, Zf[0][kt], Zf[1][kt], Zf[2][kt]);
        }

        // ---- GEMM1 + softplus block (fragments streamed from LDS) ----
        float a3p = 0.0f, q0p = 0.0f, q1p = 0.0f;
#pragma unroll 1
        for (int jt = 0; jt < 4; ++jt) {
            uint4v A00 = fA1[(      jt * 2    ) * 64 + L];
            uint4v A01 = fA1[(      jt * 2 + 1) * 64 + L];
            uint4v A10 = fA1[( 8 +  jt * 2    ) * 64 + L];
            uint4v A11 = fA1[( 8 +  jt * 2 + 1) * 64 + L];
            uint4v A20 = fA1[(16 +  jt * 2    ) * 64 + L];
            uint4v A21 = fA1[(16 +  jt * 2 + 1) * 64 + L];
            f32x4 acc0 = {0.f, 0.f, 0.f, 0.f};
            f32x4 acc1 = {0.f, 0.f, 0.f, 0.f};
            acc0 = mfma16(A00, Zf[0][0], acc0);
            acc1 = mfma16(A01, Zf[0][1], acc1);
            acc0 = mfma16(A00, Zf[1][0], acc0);
            acc1 = mfma16(A01, Zf[1][1], acc1);
            acc0 = mfma16(A10, Zf[0][0], acc0);
            acc1 = mfma16(A11, Zf[0][1], acc1);
            acc0 = mfma16(A00, Zf[2][0], acc0);
            acc1 = mfma16(A01, Zf[2][1], acc1);
            acc0 = mfma16(A10, Zf[1][0], acc0);
            acc1 = mfma16(A11, Zf[1][1], acc1);
            acc0 = mfma16(A20, Zf[0][0], acc0);
            acc1 = mfma16(A21, Zf[0][1], acc1);
            f32x4 acc = acc0 + acc1;

            float4 tq;
#pragma unroll
            for (int r = 0; r < 4; ++r) {
                int j = 16 * jt + 4 * g + r;
                float4 jc = jcp[j];
                float a2 = acc[r] + jc.x + jc.y * x.x + jc.z * x.y;
                float e = __expf(-fabsf(a2));
                float inv = __builtin_amdgcn_rcpf(1.0f + e);
                float z2 = __logf(1.0f + e) + fmaxf(a2, 0.0f);
                float s2 = (a2 >= 0.0f ? 1.0f : e) * inv;
                a3p = fmaf(jc.w, z2, a3p);
                float tv = jc.w * s2;
                q0p = fmaf(tv, jc.y, q0p);
                q1p = fmaf(tv, jc.z, q1p);
                ((float*)&tq)[r] = tv;
            }
            *(float4*)&tb[lm * TSTR + 16 * jt + 4 * g] = tq;
        }

        // ---- output layer + sigma (registers, same beta) ----
        float a3 = redg(a3p) + b3v + wim3_0 * x.x + wim3_1 * x.y;
        float qa = wim3_0 + redg(q0p);
        float qb = wim3_1 + redg(q1p);
        float e3 = __expf(-fabsf(a3));
        float inv3 = __builtin_amdgcn_rcpf(1.0f + e3);
        float hX = __logf(1.0f + e3) + fmaxf(a3, 0.0f);
        float s3 = (a3 >= 0.0f ? 1.0f : e3) * inv3;
        float h = hX - h0;
        float sigma, sigp;
        if (h >= 1.0f)      { sigma = h - 0.5f;      sigp = 1.0f; }
        else if (h > 0.0f)  { sigma = 0.5f * h * h;  sigp = h; }
        else                { sigma = 0.0f;          sigp = 0.0f; }
        float dx0 = x.x - xr0, dx1 = x.y - xr1;
        float V = sigma + EPSC * (dx0 * dx0 + dx1 * dx1);

        // ---- t fragments (same-wave LDS transpose; lgkmcnt ordering) ----
        uint4v Tf[3][2];
#pragma unroll
        for (int kt = 0; kt < 2; ++kt) {
            float tv[8];
            *(float4*)&tv[0] = *(const float4*)&tb[lm * TSTR + 32 * kt + 8 * g];
            *(float4*)&tv[4] = *(const float4*)&tb[lm * TSTR + 32 * kt + 8 * g + 4];
            split3(tv, Tf[0][kt], Tf[1][kt], Tf[2][kt]);
        }

        // ---- GEMM2 + layer-1 backprop fold ----
        float p0 = 0.0f, p1 = 0.0f;
#pragma unroll 1
        for (int it = 0; it < 4; ++it) {
            uint4v A00 = fA2[(      it * 2    ) * 64 + L];
            uint4v A01 = fA2[(      it * 2 + 1) * 64 + L];
            uint4v A10 = fA2[( 8 +  it * 2    ) * 64 + L];
            uint4v A11 = fA2[( 8 +  it * 2 + 1) * 64 + L];
            uint4v A20 = fA2[(16 +  it * 2    ) * 64 + L];
            uint4v A21 = fA2[(16 +  it * 2 + 1) * 64 + L];
            f32x4 acc0 = {0.f, 0.f, 0.f, 0.f};
            f32x4 acc1 = {0.f, 0.f, 0.f, 0.f};
            acc0 = mfma16(A00, Tf[0][0], acc0);
            acc1 = mfma16(A01, Tf[0][1], acc1);
            acc0 = mfma16(A00, Tf[1][0], acc0);
            acc1 = mfma16(A01, Tf[1][1], acc1);
            acc0 = mfma16(A10, Tf[0][0], acc0);
            acc1 = mfma16(A11, Tf[0][1], acc1);
            acc0 = mfma16(A00, Tf[2][0], acc0);
            acc1 = mfma16(A01, Tf[2][1], acc1);
            acc0 = mfma16(A10, Tf[1][0], acc0);
            acc1 = mfma16(A11, Tf[1][1], acc1);
            acc0 = mfma16(A20, Tf[0][0], acc0);
            acc1 = mfma16(A21, Tf[0][1], acc1);
            f32x4 acc = acc0 + acc1;
#pragma unroll
            for (int r = 0; r < 4; ++r) {
                int i = 16 * it + 4 * g + r;
                float4 wv = wbp[i];
                float a1 = fmaf(wv.x, x.x, fmaf(wv.y, x.y, wv.z));
                float e1 = __expf(-fabsf(a1));
                float s1 = (a1 >= 0.0f ? 1.0f : e1) * __builtin_amdgcn_rcpf(1.0f + e1);
                float c = acc[r] * s1;       // pads: acc=0 -> c=0
                p0 = fmaf(c, wv.x, p0);
                p1 = fmaf(c, wv.y, p1);
            }
        }
        float sum0 = redg(p0), sum1 = redg(p1);

        // ---- epilogue ----
        float dh0 = s3 * (qa + sum0);
        float dh1 = s3 * (qb + sum1);
        float dV0 = sigp * dh0 + 2.0f * EPSC * dx0;
        float dV1 = sigp * dh1 + 2.0f * EPSC * dx1;
        float f0 = fn0 * x.x + fn1 * x.y;
        float f1 = fn2 * x.x + fn3 * x.y;
        float gg0 = gn0 * x.x + gn1 * x.y + bg0;
        float gg1 = gn2 * x.x + gn3 * x.y + bg1;
        float scv = dV0 * f0 + dV1 * f1 + ALPHAC * V - fabsf(dV0 * gg0 + dV1 * gg1);
        float nrm = dV0 * dV0 + dV1 * dV1;
        float rr = fmaxf(scv, 0.0f) * __builtin_amdgcn_rcpf(nrm);
        float o0 = f0 - dV0 * rr + gg0 * u;
        float o1 = f1 - dV1 * rr + gg1 * u;
        if (g == 0 && sid < N) ((float2*)out)[sid] = make_float2(o0, o1);

        __builtin_amdgcn_sched_barrier(0);   // no cross-beta hoisting
    }
}

extern "C" void kernel_launch(void* const* d_in, const int* in_sizes, int n_in,
                              void* d_out, int out_size, void* d_ws, size_t ws_size,
                              hipStream_t stream) {
    // 0:X 1:U 2:Xref 3:W_fnn 4:W_gnn 5:b_gnn 6:W1 7:b1 8:W2 9:b2 10:W3 11:b3 12:Wim2 13:Wim3
    const float* X     = (const float*)d_in[0];
    const float* U     = (const float*)d_in[1];
    const float* Xref  = (const float*)d_in[2];
    const float* W_fnn = (const float*)d_in[3];
    const float* W_gnn = (const float*)d_in[4];
    const float* b_gnn = (const float*)d_in[5];
    const float* W1    = (const float*)d_in[6];
    const float* b1    = (const float*)d_in[7];
    const float* W2    = (const float*)d_in[8];
    const float* b2    = (const float*)d_in[9];
    const float* W3    = (const float*)d_in[10];
    const float* b3    = (const float*)d_in[11];
    const float* Wim2  = (const float*)d_in[12];
    const float* Wim3  = (const float*)d_in[13];

    const int N = in_sizes[0] / 2;
    float* outp = (float*)d_out;

    dho_prep<<<1, 256, 0, stream>>>(Xref, W1, b1, W2, b2, W3, b3, Wim2, Wim3, d_ws);

    const int blocks = (N + 255) / 256;
    dho_main<<<blocks, 256, 0, stream>>>(
        X, U, d_ws, W_fnn, W_gnn, b_gnn, b3, Wim3, Xref, outp, N);
}